// Round 7
// baseline (1603.744 us; speedup 1.0000x reference)
//
#include <hip/hip_runtime.h>

typedef float v2 __attribute__((ext_vector_type(2)));

#define MEMFENCE() asm volatile("" ::: "memory")

namespace {
constexpr int T = 2048;
constexpr int B = 4096;
constexpr int H = 32;
constexpr int WAVES = 4;   // waves (= batch elements) per 256-thread block
constexpr int CHUNK = 64;  // x timesteps staged per refill

struct WaveLds {
  float4 xbuf[CHUNK];  // (x0,x1,x2,_) per staged step
};
}  // namespace

__global__ __launch_bounds__(256, 4)
void lstm_fused(const float* __restrict__ x,
                const float* __restrict__ W_ih,
                const float* __restrict__ W_hh,
                const float* __restrict__ b_ih,
                const float* __restrict__ b_hh,
                float* __restrict__ out)
{
  __shared__ WaveLds lds[WAVES];
  const int lane = threadIdx.x & 63;
  const int wid  = threadIdx.x >> 6;
  const int j    = lane & 31;
  const bool low = lane < 32;            // low: gates (i,g); high: (f,o)
  const int b    = blockIdx.x * WAVES + wid;
  WaveLds& L = lds[wid];

  const int g0 = (low ? 0 : 1) * H + j;  // i-row (low) / f-row (high)
  const int g1 = (low ? 2 : 3) * H + j;  // g-row (low) / o-row (high)

  // Fold exp2-domain scaling into weights: sigmoid rows * -log2(e),
  // tanh row (g) * -2log2(e).
  const float L2E = 1.442695040888963f;
  const float s0 = -L2E;
  const float s1 = low ? -2.0f * L2E : -L2E;
  const float k2 = low ? 2.0f : 1.0f;
  const float k3 = low ? -1.0f : 0.0f;

  // Recurrent weights as (k-even, k-odd) pairs per gate, pre-scaled.
  // w0[q] = (Wg0[2q]*s0, Wg0[2q+1]*s0), w1[q] = (Wg1[2q]*s1, Wg1[2q+1]*s1)
  v2 w0[H / 2], w1[H / 2];
  {
    const float4* r0 = reinterpret_cast<const float4*>(W_hh + g0 * H);
    const float4* r1 = reinterpret_cast<const float4*>(W_hh + g1 * H);
    #pragma unroll
    for (int m = 0; m < H / 4; ++m) {
      float4 a = r0[m], d = r1[m];
      w0[2*m+0] = v2{a.x * s0, a.y * s0};
      w0[2*m+1] = v2{a.z * s0, a.w * s0};
      w1[2*m+0] = v2{d.x * s1, d.y * s1};
      w1[2*m+1] = v2{d.z * s1, d.w * s1};
    }
  }
  // input weights (I=3) and fused bias, per gate, pre-scaled
  const float u00 = W_ih[g0*3+0] * s0, u01 = W_ih[g0*3+1] * s0, u02 = W_ih[g0*3+2] * s0;
  const float u10 = W_ih[g1*3+0] * s1, u11 = W_ih[g1*3+1] * s1, u12 = W_ih[g1*3+2] * s1;
  const float bias0 = (b_ih[g0] + b_hh[g0]) * s0;
  const float bias1 = (b_ih[g1] + b_hh[g1]) * s1;

  // State: lane j (low half) holds h_j, c_j (high half's copies are don't-care;
  // readlane always targets lanes 0..31).
  float c = 0.f, h = 0.f;
  const float* xb = x + (size_t)b * T * 3;

  for (int tcb = 0; tcb < T; tcb += CHUNK) {
    MEMFENCE();
    const float* xp = xb + (size_t)(tcb + lane) * 3;
    L.xbuf[lane] = make_float4(xp[0], xp[1], xp[2], 0.f);
    MEMFENCE();

    #pragma unroll 2
    for (int s = 0; s < CHUNK; ++s) {
      const float4 xv = L.xbuf[s];  // uniform addr -> broadcast (1 DS op)
      // x contribution (scalar, 3 fma per gate) into the even slot
      float a0 = __builtin_fmaf(xv.x, u00, __builtin_fmaf(xv.y, u01, __builtin_fmaf(xv.z, u02, bias0)));
      float a1 = __builtin_fmaf(xv.x, u10, __builtin_fmaf(xv.y, u11, __builtin_fmaf(xv.z, u12, bias1)));
      v2 acc0 = {a0, 0.f};
      v2 acc1 = {a1, 0.f};

      // recurrent matmul: per k-pair, natural (h_2q, h_2q+1) SGPR-pair
      // broadcast (2 readlane -> REG_SEQUENCE) feeding packed FMAs
      const unsigned hbits = __builtin_bit_cast(unsigned, h);
      #pragma unroll
      for (int q = 0; q < H / 2; ++q) {
        unsigned ha = __builtin_amdgcn_readlane(hbits, 2 * q);
        unsigned hb = __builtin_amdgcn_readlane(hbits, 2 * q + 1);
        unsigned long long hp = ((unsigned long long)hb << 32) | ha;
        asm("v_pk_fma_f32 %0, %1, %2, %0" : "+v"(acc0) : "s"(hp), "v"(w0[q]));
        asm("v_pk_fma_f32 %0, %1, %2, %0" : "+v"(acc1) : "s"(hp), "v"(w1[q]));
      }
      float p0s = acc0.x + acc0.y;  // gate0 pre-activation (scaled)
      float p1s = acc1.x + acc1.y;  // gate1 pre-activation (scaled)

      // act0 = sigmoid; act1 = tanh (low) / sigmoid (high)
      float v0 = __builtin_amdgcn_rcpf(1.f + __builtin_amdgcn_exp2f(p0s));
      float v1 = __builtin_fmaf(
          __builtin_amdgcn_rcpf(1.f + __builtin_amdgcn_exp2f(p1s)), k2, k3);

      // bring the partner half's (sigmoid_f, sigmoid_o) to the low half
      float p0 = __shfl_xor(v0, 32, 64);  // low lanes receive sigmoid(f)
      float p1 = __shfl_xor(v1, 32, 64);  // low lanes receive sigmoid(o)

      // low half: v0=sigmoid(i), v1=tanh(g), p0=sigmoid(f), p1=sigmoid(o)
      // (high half computes garbage here; never consumed)
      c = __builtin_fmaf(p0, c, v0 * v1);
      float ec = __builtin_amdgcn_exp2f(c * (-2.0f * L2E));
      float th = __builtin_fmaf(__builtin_amdgcn_rcpf(1.f + ec), 2.f, -1.f);
      h = p1 * th;
    }
  }

  if (low) out[(size_t)b * H + j] = h;
}

extern "C" void kernel_launch(void* const* d_in, const int* in_sizes, int n_in,
                              void* d_out, int out_size, void* d_ws, size_t ws_size,
                              hipStream_t stream) {
  const float* x    = (const float*)d_in[0];
  const float* W_ih = (const float*)d_in[1];
  const float* W_hh = (const float*)d_in[2];
  const float* b_ih = (const float*)d_in[3];
  const float* b_hh = (const float*)d_in[4];
  float* out = (float*)d_out;

  dim3 grid(B / WAVES), block(256);
  hipLaunchKernelGGL(lstm_fused, grid, block, 0, stream,
                     x, W_ih, W_hh, b_ih, b_hh, out);
}